// Round 17
// baseline (271.403 us; speedup 1.0000x reference)
//
#include <hip/hip_runtime.h>

#define DEV __device__ __forceinline__

typedef _Float16 half8 __attribute__((ext_vector_type(8)));
typedef _Float16 half2v __attribute__((ext_vector_type(2)));
typedef float f32x16 __attribute__((ext_vector_type(16)));
typedef int int4v __attribute__((ext_vector_type(4)));

DEV f32x16 mfma16(half8 a, half8 b, f32x16 c) {
    return __builtin_amdgcn_mfma_f32_32x32x16_f16(a, b, c, 0, 0, 0);
}
DEV half8 h8(int4v v) { return __builtin_bit_cast(half8, v); }
DEV half8 ldh8(const _Float16* p) { return *(const half8*)p; }
DEV int pkrtz(float a, float b) {
    auto t = __builtin_amdgcn_cvt_pkrtz(a, b);
    return __builtin_bit_cast(int, t);
}
// pack two f32 -> f16x2 (RTZ), then packed relu
DEV int relupk(float a, float b) {
    int p = pkrtz(a, b);
    half2v h = __builtin_bit_cast(half2v, p);
    half2v z = {(_Float16)0.f, (_Float16)0.f};
    h = __builtin_elementwise_max(h, z);   // v_pk_max_f16
    return __builtin_bit_cast(int, h);
}

DEV f32x16 zero16() {
    f32x16 z = {0.f,0.f,0.f,0.f,0.f,0.f,0.f,0.f,0.f,0.f,0.f,0.f,0.f,0.f,0.f,0.f};
    return z;
}

struct Frags { int4v c[4]; };  // activation B-fragments, K=64 (4 chunks of 16)

// sigma-repack: with weights' k-rows permuted by sigma(k)=(k&3)+8*((k&7)>>2)+4*(k>>3)
// (an involution), the D-layout IS the next layer's B-fragment layout after f16 pack.
// No permlane, no cross-half swap: B.c[0]=C0[0..7], c[1]=C0[8..15], c[2]=C1[0..7], c[3]=C1[8..15].
DEV void repack(const f32x16& C0, const f32x16& C1, Frags& B) {
    int4v b0, b1, b2, b3;
#pragma unroll
    for (int q = 0; q < 4; ++q) {
        b0[q] = relupk(C0[2*q],     C0[2*q+1]);
        b1[q] = relupk(C0[8+2*q],   C0[9+2*q]);
        b2[q] = relupk(C1[2*q],     C1[2*q+1]);
        b3[q] = relupk(C1[8+2*q],   C1[9+2*q]);
    }
    B.c[0] = b0; B.c[1] = b1; B.c[2] = b2; B.c[3] = b3;
}

// issue the 10 ds_read_b128 for one hidden layer's A-fragments (5 chunks x 2 m-halves)
DEV void loadA5(const _Float16* base, int lam, half8* A0, half8* A1) {
    const _Float16* p0 = base + lam * 8;
    const _Float16* p1 = base + 2560 + lam * 8;
#pragma unroll
    for (int kk = 0; kk < 5; ++kk) {
        A0[kk] = ldh8(p0 + kk * 512);
        A1[kk] = ldh8(p1 + kk * 512);
    }
}

// one tile (32 rows), hidden layer: 10 MFMA burst into C0 (feats 0-31), C1 (feats 32-63)
DEV void mfma_hid_t(const half8* A0, const half8* A1, half8 ones, const Frags& Bx,
                    f32x16& C0, f32x16& C1) {
    C0 = mfma16(A0[4], ones, zero16());
    C1 = mfma16(A1[4], ones, zero16());
#pragma unroll
    for (int kk = 0; kk < 4; ++kk) {
        half8 b = h8(Bx.c[kk]);
        C0 = mfma16(A0[kk], b, C0);
        C1 = mfma16(A1[kk], b, C1);
    }
}

// one tile, input layer (K=32, bias rides in x's k=28 slot): 4 MFMA burst
DEV void mfma_in_t(const half8* I, const Frags& Bx, f32x16& C0, f32x16& C1) {
    C0 = mfma16(I[0], h8(Bx.c[0]), zero16());
    C1 = mfma16(I[2], h8(Bx.c[0]), zero16());
    C0 = mfma16(I[1], h8(Bx.c[1]), C0);
    C1 = mfma16(I[3], h8(Bx.c[1]), C1);
}

// one tile, out layer: 5 MFMA burst (features 0..20 live in m=0 half)
DEV void mfma_out_t(const half8* Ao, half8 ones, const Frags& Bx, f32x16& C) {
    C = mfma16(Ao[4], ones, zero16());
#pragma unroll
    for (int kk = 0; kk < 4; ++kk) C = mfma16(Ao[kk], h8(Bx.c[kk]), C);
}

DEV void store_out(const f32x16& C, int h, float* __restrict__ out, int row) {
    float* o = out + row * 21;
#pragma unroll
    for (int r = 0; r < 16; ++r) {
        int f = (r & 3) + 8 * (r >> 2) + 4 * h;
        if (f < 21) o[f] = __builtin_amdgcn_rcpf(1.f + __expf(-C[r]));
    }
}

DEV void load_x(const float* __restrict__ x, int row, int h, Frags& B) {
    // identity k-order (wI stored identity); k=28 slot carries 1.0 (bias rides in wI row 28)
    const float* xr = x + row * 28;
    float4 fa = *(const float4*)(xr + 8 * h);
    float4 fb = *(const float4*)(xr + 8 * h + 4);
    float4 fc = *(const float4*)(xr + 16 + 8 * h);
    float4 fd = (h == 0) ? *(const float4*)(xr + 20) : make_float4(1.f, 0.f, 0.f, 0.f);
    int4v c0, c1;
    c0[0] = pkrtz(fa.x, fa.y); c0[1] = pkrtz(fa.z, fa.w);
    c0[2] = pkrtz(fb.x, fb.y); c0[3] = pkrtz(fb.z, fb.w);
    c1[0] = pkrtz(fc.x, fc.y); c1[1] = pkrtz(fc.z, fc.w);
    c1[2] = pkrtz(fd.x, fd.y); c1[3] = pkrtz(fd.z, fd.w);
    B.c[0] = c0; B.c[1] = c1;
}

#define NT 512

__global__ __attribute__((amdgpu_flat_work_group_size(NT, NT), amdgpu_waves_per_eu(2, 2)))
void mlp_fused(
    const float* __restrict__ x, const float* __restrict__ W_in, const float* __restrict__ b_in,
    const float* __restrict__ W_hid, const float* __restrict__ b_hid,
    const float* __restrict__ W_out, const float* __restrict__ b_out,
    float* __restrict__ out) {
    // LDS weights in f16, A-fragment order: wH [l][m][kk 0..4][lam][e]; chunk kk=4 = bias column.
    // wH and wO use SIGMA-PERMUTED k within each 16-chunk (see repack); wI is identity-k.
    __shared__ __align__(16) _Float16 wH[51200];  // 10 x 2 x 5 x 64 x 8
    __shared__ __align__(16) _Float16 wI[2048];   // 2 x 2 x 64 x 8  (K=32, bias in k=28)
    __shared__ __align__(16) _Float16 wO[2560];   // 5 x 64 x 8      (features 0..20)

    const int tid = threadIdx.x;

    // zero phase: chunk-4 regions of wH, all of wI and wO
    for (int i = tid; i < 10240; i += NT) {   // wH bias chunks: [l][m][512]
        int l = i >> 10, rem = i & 1023, m = rem >> 9, off = rem & 511;
        wH[l * 5120 + m * 2560 + 2048 + off] = (_Float16)0.f;
    }
    for (int i = tid; i < 2048; i += NT) wI[i] = (_Float16)0.f;
    for (int i = tid; i < 2560; i += NT) wO[i] = (_Float16)0.f;
    __syncthreads();

    // fill phase (coalesced global reads, scattered LDS writes)
    for (int i = tid; i < 40960; i += NT) {   // W_hid [l][kin][o], sigma-permuted k placement
        int o = i & 63, kin = (i >> 6) & 63, l = i >> 12;
        int m = o >> 5, kk = kin >> 4;
        int hh = (kin >> 2) & 1;                       // sigma: kappa>>3 = (p>>2)&1
        int e = (kin & 3) + 4 * ((kin >> 3) & 1);      // sigma: kappa&7 = (p&3)+4*(p>>3)
        int lam = hh * 32 + (o & 31);
        wH[l * 5120 + m * 2560 + kk * 512 + lam * 8 + e] = (_Float16)W_hid[i];
    }
    for (int i = tid; i < 640; i += NT) {     // b_hid -> wH chunk4, kappa=0 (sigma-fixed), lam<32
        int l = i >> 6, f = i & 63, m = f >> 5, r = f & 31;
        wH[l * 5120 + m * 2560 + 2048 + r * 8] = (_Float16)b_hid[i];
    }
    for (int i = tid; i < 1792; i += NT) {    // W_in [28][64], identity k
        int o = i & 63, kin = i >> 6;
        int m = o >> 5, kk = kin >> 4, hh = (kin >> 3) & 1, e = kin & 7;
        int lam = hh * 32 + (o & 31);
        wI[m * 1024 + kk * 512 + lam * 8 + e] = (_Float16)W_in[i];
    }
    for (int i = tid; i < 64; i += NT) {      // b_in -> wI k=28 slot: kk=1, hh=1, e=4
        int m = i >> 5;
        wI[m * 1024 + 512 + (32 + (i & 31)) * 8 + 4] = (_Float16)b_in[i];
    }
    for (int i = tid; i < 1344; i += NT) {    // W_out [64][21], sigma-permuted k placement
        int o = i % 21, kin = i / 21;
        int kk = kin >> 4;
        int hh = (kin >> 2) & 1;
        int e = (kin & 3) + 4 * ((kin >> 3) & 1);
        int lam = hh * 32 + o;
        wO[kk * 512 + lam * 8 + e] = (_Float16)W_out[i];
    }
    for (int i = tid; i < 21; i += NT)        // b_out -> wO chunk4, kappa=0
        wO[4 * 512 + i * 8] = (_Float16)b_out[i];
    __syncthreads();

    const int w = tid >> 6, lam = tid & 63;
    const int col = lam & 31, h = lam >> 5;
    int4v onesv; onesv[0] = (h == 0) ? 0x3C00 : 0; onesv[1] = 0; onesv[2] = 0; onesv[3] = 0;
    half8 ones = h8(onesv);

    // hoist loop-invariant input/output layer fragments (reused by all iterations)
    half8 I[4], Ao[5];
    {
        const _Float16* p0 = wI + lam * 8;
        const _Float16* p1 = wI + 1024 + lam * 8;
        I[0] = ldh8(p0);       I[1] = ldh8(p0 + 512);
        I[2] = ldh8(p1);       I[3] = ldh8(p1 + 512);
        const _Float16* po = wO + lam * 8;
#pragma unroll
        for (int kk = 0; kk < 5; ++kk) Ao[kk] = ldh8(po + kk * 512);
    }

    // persistent: 256 blocks x 128 tiles; wave w owns tiles [w*16, w*16+16), 2 per iteration
    const int tbase = blockIdx.x * 128;
#pragma unroll 1
    for (int j = 0; j < 8; ++j) {
        int tA = tbase + w * 16 + 2 * j;
        int rowA = tA * 32 + col, rowB = rowA + 32;
        Frags BA, BB;
        load_x(x, rowA, h, BA);
        load_x(x, rowB, h, BB);

        half8 Fa0[5], Fa1[5], Fb0[5], Fb1[5];
        f32x16 CA0, CA1, CB0, CB1;

        // ---- two-stream skewed pipeline: B's burst hides A's repack, and vice versa ----
        mfma_in_t(I, BA, CA0, CA1);          // A burst (4 MFMA)
        loadA5(wH, lam, Fa0, Fa1);           // frags l=0, issued under A's burst
        mfma_in_t(I, BB, CB0, CB1);          // B burst
        repack(CA0, CA1, BA);                // A repack under B's burst

#pragma unroll
        for (int l2 = 0; l2 < 5; ++l2) {
            const _Float16* b0 = wH + (2 * l2) * 5120;
            // layer 2*l2 (frags Fa)
            mfma_hid_t(Fa0, Fa1, ones, BA, CA0, CA1);   // A burst (10 MFMA)
            loadA5(b0 + 5120, lam, Fb0, Fb1);           // prefetch layer 2*l2+1 under A's burst
            repack(CB0, CB1, BB);                       // B repack under A's burst
            mfma_hid_t(Fa0, Fa1, ones, BB, CB0, CB1);   // B burst
            repack(CA0, CA1, BA);                       // A repack under B's burst
            // layer 2*l2+1 (frags Fb)
            mfma_hid_t(Fb0, Fb1, ones, BA, CA0, CA1);   // A burst
            if (l2 < 4) loadA5(b0 + 10240, lam, Fa0, Fa1);  // prefetch layer 2*l2+2
            repack(CB0, CB1, BB);                       // B repack under A's burst
            mfma_hid_t(Fb0, Fb1, ones, BB, CB0, CB1);   // B burst
            repack(CA0, CA1, BA);                       // A repack under B's burst
        }

        // out layer
        f32x16 CoA, CoB;
        mfma_out_t(Ao, ones, BA, CoA);       // A burst (5 MFMA)
        repack(CB0, CB1, BB);                // B repack of layer 9 under A's burst
        mfma_out_t(Ao, ones, BB, CoB);       // B burst
        store_out(CoA, h, out, rowA);        // A sigmoid+store under B's burst
        store_out(CoB, h, out, rowB);
    }
}

extern "C" void kernel_launch(void* const* d_in, const int* in_sizes, int n_in,
                              void* d_out, int out_size, void* d_ws, size_t ws_size,
                              hipStream_t stream) {
    const float* x     = (const float*)d_in[0];
    const float* W_in  = (const float*)d_in[1];
    const float* b_in  = (const float*)d_in[2];
    const float* W_hid = (const float*)d_in[3];
    const float* b_hid = (const float*)d_in[4];
    const float* W_out = (const float*)d_in[5];
    const float* b_out = (const float*)d_in[6];
    float* out = (float*)d_out;
    mlp_fused<<<dim3(256), dim3(NT), 0, stream>>>(x, W_in, b_in, W_hid, b_hid, W_out, b_out, out);
}

// Round 18
// 97.430 us; speedup vs baseline: 2.7856x; 2.7856x over previous
//
#include <hip/hip_runtime.h>

#define DEV __device__ __forceinline__
#define SBAR() __builtin_amdgcn_sched_barrier(0)

typedef _Float16 half8 __attribute__((ext_vector_type(8)));
typedef _Float16 half2v __attribute__((ext_vector_type(2)));
typedef float f32x16 __attribute__((ext_vector_type(16)));
typedef int int4v __attribute__((ext_vector_type(4)));

DEV f32x16 mfma16(half8 a, half8 b, f32x16 c) {
    return __builtin_amdgcn_mfma_f32_32x32x16_f16(a, b, c, 0, 0, 0);
}
DEV half8 h8(int4v v) { return __builtin_bit_cast(half8, v); }
DEV half8 ldh8(const _Float16* p) { return *(const half8*)p; }
DEV int pkrtz(float a, float b) {
    auto t = __builtin_amdgcn_cvt_pkrtz(a, b);
    return __builtin_bit_cast(int, t);
}
// pack two f32 -> f16x2 (RTZ), then packed relu
DEV int relupk(float a, float b) {
    int p = pkrtz(a, b);
    half2v h = __builtin_bit_cast(half2v, p);
    half2v z = {(_Float16)0.f, (_Float16)0.f};
    h = __builtin_elementwise_max(h, z);   // v_pk_max_f16
    return __builtin_bit_cast(int, h);
}

DEV f32x16 zero16() {
    f32x16 z = {0.f,0.f,0.f,0.f,0.f,0.f,0.f,0.f,0.f,0.f,0.f,0.f,0.f,0.f,0.f,0.f};
    return z;
}

struct Frags { int4v c[4]; };  // activation B-fragments, K=64 (4 chunks of 16)

// sigma-repack: with weights' k-rows permuted by sigma(k)=(k&3)+8*((k&7)>>2)+4*(k>>3)
// (an involution), the D-layout IS the next layer's B-fragment layout after f16 pack.
// No permlane, no cross-half swap: B.c[0]=C0[0..7], c[1]=C0[8..15], c[2]=C1[0..7], c[3]=C1[8..15].
DEV void repack(const f32x16& C0, const f32x16& C1, Frags& B) {
    int4v b0, b1, b2, b3;
#pragma unroll
    for (int q = 0; q < 4; ++q) {
        b0[q] = relupk(C0[2*q],     C0[2*q+1]);
        b1[q] = relupk(C0[8+2*q],   C0[9+2*q]);
        b2[q] = relupk(C1[2*q],     C1[2*q+1]);
        b3[q] = relupk(C1[8+2*q],   C1[9+2*q]);
    }
    B.c[0] = b0; B.c[1] = b1; B.c[2] = b2; B.c[3] = b3;
}

// issue the 10 ds_read_b128 for one hidden layer's A-fragments (5 chunks x 2 m-halves)
DEV void loadA5(const _Float16* base, int lam, half8* A0, half8* A1) {
    const _Float16* p0 = base + lam * 8;
    const _Float16* p1 = base + 2560 + lam * 8;
#pragma unroll
    for (int kk = 0; kk < 5; ++kk) {
        A0[kk] = ldh8(p0 + kk * 512);
        A1[kk] = ldh8(p1 + kk * 512);
    }
}

// one tile (32 rows), hidden layer: 10 MFMA burst into C0 (feats 0-31), C1 (feats 32-63)
DEV void mfma_hid_t(const half8* A0, const half8* A1, half8 ones, const Frags& Bx,
                    f32x16& C0, f32x16& C1) {
    __builtin_amdgcn_s_setprio(1);
    C0 = mfma16(A0[4], ones, zero16());
    C1 = mfma16(A1[4], ones, zero16());
#pragma unroll
    for (int kk = 0; kk < 4; ++kk) {
        half8 b = h8(Bx.c[kk]);
        C0 = mfma16(A0[kk], b, C0);
        C1 = mfma16(A1[kk], b, C1);
    }
    __builtin_amdgcn_s_setprio(0);
}

// one tile, input layer (K=32, bias rides in x's k=28 slot): 4 MFMA burst
DEV void mfma_in_t(const half8* I, const Frags& Bx, f32x16& C0, f32x16& C1) {
    __builtin_amdgcn_s_setprio(1);
    C0 = mfma16(I[0], h8(Bx.c[0]), zero16());
    C1 = mfma16(I[2], h8(Bx.c[0]), zero16());
    C0 = mfma16(I[1], h8(Bx.c[1]), C0);
    C1 = mfma16(I[3], h8(Bx.c[1]), C1);
    __builtin_amdgcn_s_setprio(0);
}

// one tile, out layer: 5 MFMA burst (features 0..20 live in m=0 half)
DEV void mfma_out_t(const half8* Ao, half8 ones, const Frags& Bx, f32x16& C) {
    __builtin_amdgcn_s_setprio(1);
    C = mfma16(Ao[4], ones, zero16());
#pragma unroll
    for (int kk = 0; kk < 4; ++kk) C = mfma16(Ao[kk], h8(Bx.c[kk]), C);
    __builtin_amdgcn_s_setprio(0);
}

DEV void store_out(const f32x16& C, int h, float* __restrict__ out, int row) {
    float* o = out + row * 21;
#pragma unroll
    for (int r = 0; r < 16; ++r) {
        int f = (r & 3) + 8 * (r >> 2) + 4 * h;
        if (f < 21) o[f] = __builtin_amdgcn_rcpf(1.f + __expf(-C[r]));
    }
}

DEV void load_x(const float* __restrict__ x, int row, int h, Frags& B) {
    // identity k-order (wI stored identity); k=28 slot carries 1.0 (bias rides in wI row 28)
    const float* xr = x + row * 28;
    float4 fa = *(const float4*)(xr + 8 * h);
    float4 fb = *(const float4*)(xr + 8 * h + 4);
    float4 fc = *(const float4*)(xr + 16 + 8 * h);
    float4 fd = (h == 0) ? *(const float4*)(xr + 20) : make_float4(1.f, 0.f, 0.f, 0.f);
    int4v c0, c1;
    c0[0] = pkrtz(fa.x, fa.y); c0[1] = pkrtz(fa.z, fa.w);
    c0[2] = pkrtz(fb.x, fb.y); c0[3] = pkrtz(fb.z, fb.w);
    c1[0] = pkrtz(fc.x, fc.y); c1[1] = pkrtz(fc.z, fc.w);
    c1[2] = pkrtz(fd.x, fd.y); c1[3] = pkrtz(fd.z, fd.w);
    B.c[0] = c0; B.c[1] = c1;
}

#define NT 512

__global__ __attribute__((amdgpu_flat_work_group_size(NT, NT), amdgpu_waves_per_eu(2, 2)))
void mlp_fused(
    const float* __restrict__ x, const float* __restrict__ W_in, const float* __restrict__ b_in,
    const float* __restrict__ W_hid, const float* __restrict__ b_hid,
    const float* __restrict__ W_out, const float* __restrict__ b_out,
    float* __restrict__ out) {
    // LDS weights in f16, A-fragment order: wH [l][m][kk 0..4][lam][e]; chunk kk=4 = bias column.
    // wH and wO use SIGMA-PERMUTED k within each 16-chunk (see repack); wI is identity-k.
    __shared__ __align__(16) _Float16 wH[51200];  // 10 x 2 x 5 x 64 x 8
    __shared__ __align__(16) _Float16 wI[2048];   // 2 x 2 x 64 x 8  (K=32, bias in k=28)
    __shared__ __align__(16) _Float16 wO[2560];   // 5 x 64 x 8      (features 0..20)

    const int tid = threadIdx.x;

    // zero phase: chunk-4 regions of wH, all of wI and wO
    for (int i = tid; i < 10240; i += NT) {   // wH bias chunks: [l][m][512]
        int l = i >> 10, rem = i & 1023, m = rem >> 9, off = rem & 511;
        wH[l * 5120 + m * 2560 + 2048 + off] = (_Float16)0.f;
    }
    for (int i = tid; i < 2048; i += NT) wI[i] = (_Float16)0.f;
    for (int i = tid; i < 2560; i += NT) wO[i] = (_Float16)0.f;
    __syncthreads();

    // fill phase (coalesced global reads, scattered LDS writes)
    for (int i = tid; i < 40960; i += NT) {   // W_hid [l][kin][o], sigma-permuted k placement
        int o = i & 63, kin = (i >> 6) & 63, l = i >> 12;
        int m = o >> 5, kk = kin >> 4;
        int hh = (kin >> 2) & 1;                       // sigma: kappa>>3 = (p>>2)&1
        int e = (kin & 3) + 4 * ((kin >> 3) & 1);      // sigma: kappa&7 = (p&3)+4*(p>>3)
        int lam = hh * 32 + (o & 31);
        wH[l * 5120 + m * 2560 + kk * 512 + lam * 8 + e] = (_Float16)W_hid[i];
    }
    for (int i = tid; i < 640; i += NT) {     // b_hid -> wH chunk4, kappa=0 (sigma-fixed), lam<32
        int l = i >> 6, f = i & 63, m = f >> 5, r = f & 31;
        wH[l * 5120 + m * 2560 + 2048 + r * 8] = (_Float16)b_hid[i];
    }
    for (int i = tid; i < 1792; i += NT) {    // W_in [28][64], identity k
        int o = i & 63, kin = i >> 6;
        int m = o >> 5, kk = kin >> 4, hh = (kin >> 3) & 1, e = kin & 7;
        int lam = hh * 32 + (o & 31);
        wI[m * 1024 + kk * 512 + lam * 8 + e] = (_Float16)W_in[i];
    }
    for (int i = tid; i < 64; i += NT) {      // b_in -> wI k=28 slot: kk=1, hh=1, e=4
        int m = i >> 5;
        wI[m * 1024 + 512 + (32 + (i & 31)) * 8 + 4] = (_Float16)b_in[i];
    }
    for (int i = tid; i < 1344; i += NT) {    // W_out [64][21], sigma-permuted k placement
        int o = i % 21, kin = i / 21;
        int kk = kin >> 4;
        int hh = (kin >> 2) & 1;
        int e = (kin & 3) + 4 * ((kin >> 3) & 1);
        int lam = hh * 32 + o;
        wO[kk * 512 + lam * 8 + e] = (_Float16)W_out[i];
    }
    for (int i = tid; i < 21; i += NT)        // b_out -> wO chunk4, kappa=0
        wO[4 * 512 + i * 8] = (_Float16)b_out[i];
    __syncthreads();

    const int w = tid >> 6, lam = tid & 63;
    const int col = lam & 31, h = lam >> 5;
    int4v onesv; onesv[0] = (h == 0) ? 0x3C00 : 0; onesv[1] = 0; onesv[2] = 0; onesv[3] = 0;
    half8 ones = h8(onesv);

    // hoist loop-invariant input/output layer fragments (reused by all iterations)
    half8 I[4], Ao[5];
    {
        const _Float16* p0 = wI + lam * 8;
        const _Float16* p1 = wI + 1024 + lam * 8;
        I[0] = ldh8(p0);       I[1] = ldh8(p0 + 512);
        I[2] = ldh8(p1);       I[3] = ldh8(p1 + 512);
        const _Float16* po = wO + lam * 8;
#pragma unroll
        for (int kk = 0; kk < 5; ++kk) Ao[kk] = ldh8(po + kk * 512);
    }

    // persistent: 256 blocks x 128 tiles; wave w owns tiles [w*16, w*16+16), 2 per iteration
    const int tbase = blockIdx.x * 128;
#pragma unroll 1
    for (int j = 0; j < 8; ++j) {
        int tA = tbase + w * 16 + 2 * j;
        int rowA = tA * 32 + col, rowB = rowA + 32;
        Frags BA, BB;
        load_x(x, rowA, h, BA);
        load_x(x, rowB, h, BB);

        half8 Fa0[5], Fa1[5], Fb0[5], Fb1[5];
        f32x16 CA0, CA1, CB0, CB1;

        // ---- two-stream skewed pipeline with SBAR fences: each fence pins a
        // {burst ; prefetch ; repack} chunk so repacks finish inside their chunk and
        // accumulator live ranges stay short (R17's spill storm came from sinking) ----
        mfma_in_t(I, BA, CA0, CA1);          // A burst (4 MFMA)
        loadA5(wH, lam, Fa0, Fa1);           // frags l=0, issued under A's burst
        mfma_in_t(I, BB, CB0, CB1);          // B burst
        repack(CA0, CA1, BA);                // A repack under B's burst
        SBAR();

#pragma unroll
        for (int l2 = 0; l2 < 5; ++l2) {
            const _Float16* b0 = wH + (2 * l2) * 5120;
            // layer 2*l2 (frags Fa)
            mfma_hid_t(Fa0, Fa1, ones, BA, CA0, CA1);   // A burst (10 MFMA)
            loadA5(b0 + 5120, lam, Fb0, Fb1);           // prefetch layer 2*l2+1 under A's burst
            repack(CB0, CB1, BB);                       // B repack under A's burst
            SBAR();
            mfma_hid_t(Fa0, Fa1, ones, BB, CB0, CB1);   // B burst
            repack(CA0, CA1, BA);                       // A repack under B's burst
            SBAR();
            // layer 2*l2+1 (frags Fb)
            mfma_hid_t(Fb0, Fb1, ones, BA, CA0, CA1);   // A burst
            if (l2 < 4) loadA5(b0 + 10240, lam, Fa0, Fa1);  // prefetch layer 2*l2+2
            repack(CB0, CB1, BB);                       // B repack under A's burst
            SBAR();
            mfma_hid_t(Fb0, Fb1, ones, BB, CB0, CB1);   // B burst
            repack(CA0, CA1, BA);                       // A repack under B's burst
            SBAR();
        }

        // out layer
        f32x16 CoA, CoB;
        mfma_out_t(Ao, ones, BA, CoA);       // A burst (5 MFMA)
        repack(CB0, CB1, BB);                // B repack of layer 9 under A's burst
        SBAR();
        mfma_out_t(Ao, ones, BB, CoB);       // B burst
        store_out(CoA, h, out, rowA);        // A sigmoid+store under B's burst
        store_out(CoB, h, out, rowB);
    }
}

extern "C" void kernel_launch(void* const* d_in, const int* in_sizes, int n_in,
                              void* d_out, int out_size, void* d_ws, size_t ws_size,
                              hipStream_t stream) {
    const float* x     = (const float*)d_in[0];
    const float* W_in  = (const float*)d_in[1];
    const float* b_in  = (const float*)d_in[2];
    const float* W_hid = (const float*)d_in[3];
    const float* b_hid = (const float*)d_in[4];
    const float* W_out = (const float*)d_in[5];
    const float* b_out = (const float*)d_in[6];
    float* out = (float*)d_out;
    mlp_fused<<<dim3(256), dim3(NT), 0, stream>>>(x, W_in, b_in, W_hid, b_hid, W_out, b_out, out);
}